// Round 1
// baseline (1043.272 us; speedup 1.0000x reference)
//
#include <hip/hip_runtime.h>

// ---------------- constants ----------------
#define R_TOTAL 327360
#define LAB_OFF 3273600   // 2*R*5
#define MAT_OFF 3928320   // LAB_OFF + 2*R

static __device__ const int    D_LOG2G[5] = {7, 6, 5, 4, 3};
static __device__ const size_t D_TOFF[5]  = {0, 8388608, 10485760, 11010048, 11141120};
static __device__ const int    D_AOFF[5]  = {0, 245760, 307200, 322560, 326400};

// w,h per anchor type a = size_idx*3 + ratio_idx  (double-derived, rounded to f32)
static __device__ const float D_WH[15][2] = {
  {22.627416997969522f, 45.254833995939045f}, {32.f, 32.f},   {45.254833995939045f, 22.627416997969522f},
  {45.254833995939045f, 90.50966799187809f},  {64.f, 64.f},   {90.50966799187809f, 45.254833995939045f},
  {90.50966799187809f, 181.01933598375618f},  {128.f, 128.f}, {181.01933598375618f, 90.50966799187809f},
  {181.01933598375618f, 362.03867196751236f}, {256.f, 256.f}, {362.03867196751236f, 181.01933598375618f},
  {362.03867196751236f, 724.0773439350247f},  {512.f, 512.f}, {724.0773439350247f, 362.03867196751236f},
};

// ---------------- anchor decode (contract OFF: must match numpy f32 bit-exactly) ---
__device__ inline void anchor_box(int r, float& x1, float& y1, float& x2, float& y2) {
  #pragma clang fp contract(off)
  int off, lg;
  if (r < 245760)      { off = 0;      lg = 7; }
  else if (r < 307200) { off = 245760; lg = 6; }
  else if (r < 322560) { off = 307200; lg = 5; }
  else if (r < 326400) { off = 322560; lg = 4; }
  else                 { off = 326400; lg = 3; }
  int rem  = r - off;
  int a    = rem >> (2 * lg);
  int rem2 = rem & ((1 << (2 * lg)) - 1);
  int i = rem2 >> lg;
  int j = rem2 & ((1 << lg) - 1);
  float stride = (float)(512 >> lg);
  float cx = (float)i * stride;
  float cy = (float)j * stride;
  float hw = D_WH[a][0] * 0.5f;
  float hh = D_WH[a][1] * 0.5f;
  x1 = cx - hw; y1 = cy - hh; x2 = cx + hw; y2 = cy + hh;
}

__device__ inline float iou_f(float ax1, float ay1, float ax2, float ay2,
                              float bx1, float by1, float bx2, float by2) {
  #pragma clang fp contract(off)
  float ltx = fmaxf(ax1, bx1), lty = fmaxf(ay1, by1);
  float rbx = fminf(ax2, bx2), rby = fminf(ay2, by2);
  float iw = fmaxf(rbx - ltx, 0.f);
  float ih = fmaxf(rby - lty, 0.f);
  float inter = iw * ih;
  float aa = (ax2 - ax1) * (ay2 - ay1);
  float ab = (bx2 - bx1) * (by2 - by1);
  return inter / (aa + ab - inter);
}

// ---------------- kernel: transpose conv_w [co][ci][tap] -> [tap][ci][co] ----------
__global__ __launch_bounds__(256) void transpose_w_kernel(const float* __restrict__ cw,
                                                          float* __restrict__ wT) {
  int idx = blockIdx.x * 256 + threadIdx.x;   // < 589824
  int tap = idx >> 16;
  int rem = idx & 65535;
  int ci  = rem >> 8;
  int co  = rem & 255;
  wT[idx] = cw[co * 2304 + ci * 9 + tap];
}

// ---------------- kernel: 3x3 conv + bias + relu  (shifted-GEMM, fp32) -------------
// blocks per level (BM=64 co x BN=64 spatial, 2 images): 2048,512,128,32,8 -> cum below
__global__ __launch_bounds__(256) void conv3x3_kernel(
    const float* __restrict__ f0, const float* __restrict__ f1,
    const float* __restrict__ f2, const float* __restrict__ f3,
    const float* __restrict__ f4,
    const float* __restrict__ wT, const float* __restrict__ cb,
    float* __restrict__ t) {
  __shared__ float As[32][64];
  __shared__ float Bs[32][64];
  int bid = blockIdx.x;
  int l, base;
  if (bid < 2048)      { l = 0; base = 0; }
  else if (bid < 2560) { l = 1; base = 2048; }
  else if (bid < 2688) { l = 2; base = 2560; }
  else if (bid < 2720) { l = 3; base = 2688; }
  else                 { l = 4; base = 2720; }
  const int lg  = D_LOG2G[l];
  const int g   = 1 << lg;
  const int HW  = 1 << (2 * lg);
  const int lnb = 2 * lg - 6;              // log2(spatial blocks per image)
  int blk = bid - base;
  int b   = blk >> (lnb + 2);
  int r2  = blk & ((1 << (lnb + 2)) - 1);
  int co0 = (r2 >> lnb) << 6;
  int p0  = (r2 & ((1 << lnb) - 1)) << 6;
  const float* fsel = (l == 0) ? f0 : (l == 1) ? f1 : (l == 2) ? f2 : (l == 3) ? f3 : f4;
  const float* fb = fsel + (size_t)b * (size_t)(256 * HW);

  const int tid  = threadIdx.x;
  const int c    = tid & 63;
  const int krow = tid >> 6;               // 0..3
  const int p    = p0 + c;
  const int h    = p >> lg;
  const int w    = p & (g - 1);
  const int tm4  = (tid >> 4) << 2;        // row block 0..60
  const int tn4  = (tid & 15) << 2;        // col block 0..60

  float acc[4][4] = {{0.f}};

  for (int tap = 0; tap < 9; ++tap) {
    const int dh = tap / 3 - 1, dw = tap % 3 - 1;
    const int sh = h + dh, sw = w + dw;
    const bool valid = ((unsigned)sh < (unsigned)g) && ((unsigned)sw < (unsigned)g);
    const int sp = valid ? sh * g + sw : 0;  // safe clamped address
    const float* wt = wT + tap * 65536 + co0;
    for (int c8 = 0; c8 < 8; ++c8) {
      const int ci0 = c8 << 5;
      __syncthreads();
      #pragma unroll
      for (int i = 0; i < 8; ++i) {
        const int kk = krow + (i << 2);
        As[kk][c] = wt[(ci0 + kk) * 256 + c];
        float v = fb[(size_t)(ci0 + kk) * HW + sp];
        Bs[kk][c] = valid ? v : 0.f;
      }
      __syncthreads();
      #pragma unroll
      for (int kk = 0; kk < 32; ++kk) {
        const float4 av = *(const float4*)&As[kk][tm4];
        const float4 bv = *(const float4*)&Bs[kk][tn4];
        acc[0][0] += av.x * bv.x; acc[0][1] += av.x * bv.y;
        acc[0][2] += av.x * bv.z; acc[0][3] += av.x * bv.w;
        acc[1][0] += av.y * bv.x; acc[1][1] += av.y * bv.y;
        acc[1][2] += av.y * bv.z; acc[1][3] += av.y * bv.w;
        acc[2][0] += av.z * bv.x; acc[2][1] += av.z * bv.y;
        acc[2][2] += av.z * bv.z; acc[2][3] += av.z * bv.w;
        acc[3][0] += av.w * bv.x; acc[3][1] += av.w * bv.y;
        acc[3][2] += av.w * bv.z; acc[3][3] += av.w * bv.w;
      }
    }
  }
  float* tb = t + D_TOFF[l] + (size_t)b * (size_t)(256 * HW);
  #pragma unroll
  for (int rr = 0; rr < 4; ++rr) {
    const float bias = cb[co0 + tm4 + rr];
    float4 o;
    o.x = fmaxf(acc[rr][0] + bias, 0.f);
    o.y = fmaxf(acc[rr][1] + bias, 0.f);
    o.z = fmaxf(acc[rr][2] + bias, 0.f);
    o.w = fmaxf(acc[rr][3] + bias, 0.f);
    *(float4*)&tb[(size_t)(co0 + tm4 + rr) * HW + p0 + tn4] = o;
  }
}

// ---------------- kernel: 1x1 heads -> preds[b][r][5] ------------------------------
// 32 positions per block; blocks per level (x2 images): 1024,256,64,16,4 -> cum below
__global__ __launch_bounds__(256) void head_kernel(
    const float* __restrict__ t,
    const float* __restrict__ cls_w, const float* __restrict__ cls_b,
    const float* __restrict__ box_w, const float* __restrict__ box_b,
    float* __restrict__ out) {
  __shared__ float Ts[256][32];
  int bid = blockIdx.x;
  int l, base;
  if (bid < 1024)      { l = 0; base = 0; }
  else if (bid < 1280) { l = 1; base = 1024; }
  else if (bid < 1344) { l = 2; base = 1280; }
  else if (bid < 1360) { l = 3; base = 1344; }
  else                 { l = 4; base = 1360; }
  const int lg  = D_LOG2G[l];
  const int HW  = 1 << (2 * lg);
  const int lnb = 2 * lg - 5;
  int blk = bid - base;
  int b   = blk >> lnb;
  int p0  = (blk & ((1 << lnb) - 1)) << 5;
  const float* tb = t + D_TOFF[l] + (size_t)b * (size_t)(256 * HW);
  const int tid = threadIdx.x;
  #pragma unroll
  for (int i = 0; i < 32; ++i) {
    int idx = tid + (i << 8);
    int pp  = idx & 31;
    int ci  = idx >> 5;
    Ts[ci][pp] = tb[(size_t)ci * HW + p0 + pp];
  }
  __syncthreads();
  const int p   = tid & 31;
  const int grp = tid >> 5;   // 0..7
  const int pg  = p0 + p;
  const size_t aoff = (size_t)D_AOFF[l];
  for (int oc = grp; oc < 75; oc += 8) {
    const float* wr  = (oc < 15) ? (cls_w + oc * 256) : (box_w + (oc - 15) * 256);
    const float bias = (oc < 15) ? cls_b[oc] : box_b[oc - 15];
    const float4* wr4 = (const float4*)wr;
    float acc = 0.f;
    #pragma unroll 8
    for (int c4 = 0; c4 < 64; ++c4) {
      float4 wv = wr4[c4];
      int ci = c4 << 2;
      acc += wv.x * Ts[ci][p];
      acc += wv.y * Ts[ci + 1][p];
      acc += wv.z * Ts[ci + 2][p];
      acc += wv.w * Ts[ci + 3][p];
    }
    acc += bias;
    size_t r; int comp;
    if (oc < 15) { r = aoff + (size_t)oc * HW + pg; comp = 0; }
    else { int o2 = oc - 15; r = aoff + (size_t)(o2 >> 2) * HW + pg; comp = 1 + (o2 & 3); }
    out[((size_t)b * R_TOTAL + r) * 5 + comp] = acc;
  }
}

// ---------------- kernel: per-anchor labels + matched ------------------------------
__global__ __launch_bounds__(256) void label_kernel(const float* __restrict__ gt,
                                                    float* __restrict__ out) {
  #pragma clang fp contract(off)
  __shared__ float gx[32][4];
  const int b = blockIdx.y;
  const int tid = threadIdx.x;
  if (tid < 32) {
    const float* gp = gt + ((size_t)b * 32 + tid) * 4;
    float x = gp[0], y = gp[1], w = gp[2], h = gp[3];
    gx[tid][0] = x; gx[tid][1] = y; gx[tid][2] = x + w; gx[tid][3] = y + h;
  }
  __syncthreads();
  int r = blockIdx.x * 256 + tid;
  if (r >= R_TOTAL) return;
  float ax1, ay1, ax2, ay2;
  anchor_box(r, ax1, ay1, ax2, ay2);
  float best = -1e30f; int bi = 0;
  for (int n = 0; n < 32; ++n) {
    float v = iou_f(ax1, ay1, ax2, ay2, gx[n][0], gx[n][1], gx[n][2], gx[n][3]);
    if (v > best) { best = v; bi = n; }    // first-max (matches jnp.argmax)
  }
  float lab = (best < 0.3f) ? 0.f : ((best > 0.7f) ? 1.f : -1.f);
  out[LAB_OFF + (size_t)b * R_TOTAL + r] = lab;
  float4 m; m.x = gx[bi][0]; m.y = gx[bi][1]; m.z = gx[bi][2]; m.w = gx[bi][3];
  *(float4*)&out[MAT_OFF + ((size_t)b * R_TOTAL + r) * 4] = m;
}

// ---------------- kernel: per-gt best-anchor partial argmax ------------------------
// grid = 64 (b,n) pairs * 8 chunks; chunk covers 40920 anchors (8*40920 = R exactly)
__global__ __launch_bounds__(256) void argmax_part_kernel(const float* __restrict__ gt,
                                                          float2* __restrict__ part) {
  #pragma clang fp contract(off)
  const int bn = blockIdx.x >> 3, chunk = blockIdx.x & 7;
  const int b = bn >> 5, n = bn & 31;
  const float* gp = gt + ((size_t)b * 32 + n) * 4;
  const float bx1 = gp[0], by1 = gp[1];
  const float bx2 = bx1 + gp[2], by2 = by1 + gp[3];
  const int r0 = chunk * 40920;
  float best = -1e30f; int bi = 0;
  for (int r = r0 + threadIdx.x; r < r0 + 40920; r += 256) {
    float ax1, ay1, ax2, ay2;
    anchor_box(r, ax1, ay1, ax2, ay2);
    float v = iou_f(ax1, ay1, ax2, ay2, bx1, by1, bx2, by2);
    if (v > best) { best = v; bi = r; }
  }
  __shared__ float sv[256];
  __shared__ int   si[256];
  sv[threadIdx.x] = best; si[threadIdx.x] = bi;
  __syncthreads();
  for (int s = 128; s > 0; s >>= 1) {
    if ((int)threadIdx.x < s) {
      float v2 = sv[threadIdx.x + s]; int i2 = si[threadIdx.x + s];
      float v1 = sv[threadIdx.x];     int i1 = si[threadIdx.x];
      if (v2 > v1 || (v2 == v1 && i2 < i1)) { sv[threadIdx.x] = v2; si[threadIdx.x] = i2; }
    }
    __syncthreads();
  }
  if (threadIdx.x == 0) part[blockIdx.x] = make_float2(sv[0], __int_as_float(si[0]));
}

// ---------------- kernel: finalize forced-positive labels --------------------------
__global__ __launch_bounds__(64) void argmax_final_kernel(const float* __restrict__ gt,
                                                          const float2* __restrict__ part,
                                                          float* __restrict__ out) {
  #pragma clang fp contract(off)
  const int t = threadIdx.x;
  if (t >= 64) return;
  const int b = t >> 5;
  float best = -1e30f; int bi = 0;
  for (int c = 0; c < 8; ++c) {          // ascending chunks: strict > keeps first-max
    float2 pv = part[t * 8 + c];
    if (pv.x > best) { best = pv.x; bi = __float_as_int(pv.y); }
  }
  float ax1, ay1, ax2, ay2;
  anchor_box(bi, ax1, ay1, ax2, ay2);
  float score = -1e30f;
  for (int n2 = 0; n2 < 32; ++n2) {
    const float* gp = gt + ((size_t)b * 32 + n2) * 4;
    float v = iou_f(ax1, ay1, ax2, ay2, gp[0], gp[1], gp[0] + gp[2], gp[1] + gp[3]);
    score = fmaxf(score, v);
  }
  // labels = score<0.3 ? 0 : (pos ? 1 : -1); forced pos => 1 unless neg wins
  out[LAB_OFF + (size_t)b * R_TOTAL + bi] = (score < 0.3f) ? 0.f : 1.f;
}

// ---------------- launch -----------------------------------------------------------
extern "C" void kernel_launch(void* const* d_in, const int* in_sizes, int n_in,
                              void* d_out, int out_size, void* d_ws, size_t ws_size,
                              hipStream_t stream) {
  const float* f0     = (const float*)d_in[1];
  const float* f1     = (const float*)d_in[2];
  const float* f2     = (const float*)d_in[3];
  const float* f3     = (const float*)d_in[4];
  const float* f4     = (const float*)d_in[5];
  const float* gt     = (const float*)d_in[6];
  const float* conv_w = (const float*)d_in[7];
  const float* conv_b = (const float*)d_in[8];
  const float* cls_w  = (const float*)d_in[9];
  const float* cls_b  = (const float*)d_in[10];
  const float* box_w  = (const float*)d_in[11];
  const float* box_b  = (const float*)d_in[12];
  float* out = (float*)d_out;
  float* ws  = (float*)d_ws;

  float*  wT   = ws;                         // 589824 floats
  float*  t    = ws + 589824;                // 11173888 floats
  float2* part = (float2*)(ws + 589824 + 11173888);  // 512 float2

  transpose_w_kernel<<<2304, 256, 0, stream>>>(conv_w, wT);
  conv3x3_kernel<<<2728, 256, 0, stream>>>(f0, f1, f2, f3, f4, wT, conv_b, t);
  head_kernel<<<1364, 256, 0, stream>>>(t, cls_w, cls_b, box_w, box_b, out);
  label_kernel<<<dim3(1279, 2), 256, 0, stream>>>(gt, out);
  argmax_part_kernel<<<512, 256, 0, stream>>>(gt, part);
  argmax_final_kernel<<<1, 64, 0, stream>>>(gt, part, out);
}

// Round 2
// 380.342 us; speedup vs baseline: 2.7430x; 2.7430x over previous
//
#include <hip/hip_runtime.h>

typedef unsigned short u16;
typedef unsigned char  u8;
typedef unsigned int   u32;
typedef __bf16 bf16x8 __attribute__((ext_vector_type(8)));
typedef float  f32x4  __attribute__((ext_vector_type(4)));
typedef u16    u16x8  __attribute__((ext_vector_type(8)));

// ---------------- constants ----------------
#define R_TOTAL 327360
#define LAB_OFF 3273600   // 2*R*5
#define MAT_OFF 3928320   // LAB_OFF + 2*R

static __device__ const int    D_LOG2G[5] = {7, 6, 5, 4, 3};
static __device__ const size_t D_TOFF[5]  = {0, 8388608, 10485760, 11010048, 11141120};
static __device__ const size_t D_FTOFF[5] = {0, 8389120, 10486784, 11011584, 11143168};
static __device__ const int    D_AOFF[5]  = {0, 245760, 307200, 322560, 326400};

static __device__ const float D_WH[15][2] = {
  {22.627416997969522f, 45.254833995939045f}, {32.f, 32.f},   {45.254833995939045f, 22.627416997969522f},
  {45.254833995939045f, 90.50966799187809f},  {64.f, 64.f},   {90.50966799187809f, 45.254833995939045f},
  {90.50966799187809f, 181.01933598375618f},  {128.f, 128.f}, {181.01933598375618f, 90.50966799187809f},
  {181.01933598375618f, 362.03867196751236f}, {256.f, 256.f}, {362.03867196751236f, 181.01933598375618f},
  {362.03867196751236f, 724.0773439350247f},  {512.f, 512.f}, {724.0773439350247f, 362.03867196751236f},
};

__device__ __forceinline__ u16 f2bf(float x) {          // RNE f32->bf16
  u32 u = __float_as_uint(x);
  u32 r = u + 0x7FFFu + ((u >> 16) & 1u);
  return (u16)(r >> 16);
}
__device__ __forceinline__ float bf2f(u16 v) { return __uint_as_float(((u32)v) << 16); }

__device__ __forceinline__ void glds16(const void* g, void* l) {
  __builtin_amdgcn_global_load_lds(
      (const __attribute__((address_space(1))) u32*)g,
      (__attribute__((address_space(3))) u32*)l, 16, 0, 0);
}

// ---------------- anchor decode (contract OFF) ----------------
__device__ inline void anchor_box(int r, float& x1, float& y1, float& x2, float& y2) {
  #pragma clang fp contract(off)
  int off, lg;
  if (r < 245760)      { off = 0;      lg = 7; }
  else if (r < 307200) { off = 245760; lg = 6; }
  else if (r < 322560) { off = 307200; lg = 5; }
  else if (r < 326400) { off = 322560; lg = 4; }
  else                 { off = 326400; lg = 3; }
  int rem  = r - off;
  int a    = rem >> (2 * lg);
  int rem2 = rem & ((1 << (2 * lg)) - 1);
  int i = rem2 >> lg;
  int j = rem2 & ((1 << lg) - 1);
  float stride = (float)(512 >> lg);
  float cx = (float)i * stride;
  float cy = (float)j * stride;
  float hw = D_WH[a][0] * 0.5f;
  float hh = D_WH[a][1] * 0.5f;
  x1 = cx - hw; y1 = cy - hh; x2 = cx + hw; y2 = cy + hh;
}

__device__ inline float iou_f(float ax1, float ay1, float ax2, float ay2,
                              float bx1, float by1, float bx2, float by2) {
  #pragma clang fp contract(off)
  float ltx = fmaxf(ax1, bx1), lty = fmaxf(ay1, by1);
  float rbx = fminf(ax2, bx2), rby = fminf(ay2, by2);
  float iw = fmaxf(rbx - ltx, 0.f);
  float ih = fmaxf(rby - lty, 0.f);
  float inter = iw * ih;
  float aa = (ax2 - ax1) * (ay2 - ay1);
  float ab = (bx2 - bx1) * (by2 - by1);
  return inter / (aa + ab - inter);
}

// ---------------- kernel: pack conv_w -> bf16 [ks][co][32] with quarter swizzle ----
// swizzle: data quarter qd stored at dq = qd ^ ((co>>1)&3)
__global__ __launch_bounds__(256) void pack_w_kernel(const float* __restrict__ cw,
                                                     u16* __restrict__ wp) {
  int idx = blockIdx.x * 256 + threadIdx.x;   // < 589824
  int ks  = idx >> 13;
  int rem = idx & 8191;
  int co  = rem >> 5;
  int k   = rem & 31;
  int tap = ks >> 3;
  int cb  = ks & 7;
  float v = cw[co * 2304 + (cb * 32 + k) * 9 + tap];
  int qd = k >> 3, wi = k & 7;
  int dq = qd ^ ((co >> 1) & 3);
  wp[(size_t)ks * 8192 + co * 32 + dq * 8 + wi] = f2bf(v);
}

// ---------------- kernel: features [b][ci][p] f32 -> [b][p][ci] bf16 (+zero row) ---
__global__ __launch_bounds__(256) void feat_pack_kernel(
    const float* __restrict__ f0, const float* __restrict__ f1,
    const float* __restrict__ f2, const float* __restrict__ f3,
    const float* __restrict__ f4, u16* __restrict__ Ft) {
  __shared__ float tile[64][65];
  int bid = blockIdx.x;
  int l, base, nb1;
  if (bid < 514)      { l = 0; base = 0;   nb1 = 257; }
  else if (bid < 644) { l = 1; base = 514; nb1 = 65; }
  else if (bid < 678) { l = 2; base = 644; nb1 = 17; }
  else if (bid < 688) { l = 3; base = 678; nb1 = 5; }
  else                { l = 4; base = 688; nb1 = 2; }
  const int lg = D_LOG2G[l];
  const int HW = 1 << (2 * lg);
  int blk = bid - base;
  int b   = blk / nb1;
  int p0  = (blk - b * nb1) * 64;
  u16* dst = Ft + D_FTOFF[l];
  const int tid = threadIdx.x;
  if (p0 >= HW) {      // zero halo row
    if (tid < 32) {
      u16x8 z = (u16x8)0;
      *(u16x8*)(dst + ((size_t)b * (HW + 1) + HW) * 256 + tid * 8) = z;
    }
    return;
  }
  const float* fsel = (l == 0) ? f0 : (l == 1) ? f1 : (l == 2) ? f2 : (l == 3) ? f3 : f4;
  const float* fb = fsel + (size_t)b * 256 * HW;
  for (int cg = 0; cg < 4; ++cg) {
    __syncthreads();
    #pragma unroll
    for (int i = 0; i < 16; ++i) {
      int idx = i * 256 + tid;
      int cl = idx >> 6, pp = idx & 63;
      tile[cl][pp] = fb[(size_t)(cg * 64 + cl) * HW + p0 + pp];
    }
    __syncthreads();
    #pragma unroll
    for (int i = 0; i < 2; ++i) {
      int slot = i * 256 + tid;
      int pos = slot >> 3, ch = slot & 7;
      u16x8 v;
      #pragma unroll
      for (int j = 0; j < 8; ++j) v[j] = f2bf(tile[ch * 8 + j][pos]);
      *(u16x8*)(dst + ((size_t)b * (HW + 1) + p0 + pos) * 256 + cg * 64 + ch * 8) = v;
    }
  }
}

// ---------------- kernel: 3x3 conv via bf16 MFMA, BM=128 co x BN=64 pos, BK=32 -----
// 2 waves; wave tile 64x64 (16 mfma : 8 ds_read per K-step). 72 K-steps (9 taps x 8).
__global__ __launch_bounds__(128) void conv_mfma_kernel(
    const u16* __restrict__ Ft, const u16* __restrict__ wp,
    const float* __restrict__ cb, u16* __restrict__ t) {
  __shared__ __align__(16) u8 Asb[8192];
  __shared__ __align__(16) u8 Bsb[4096];
  const int bid = blockIdx.x;
  int l, base;
  if (bid < 1024)      { l = 0; base = 0; }
  else if (bid < 1280) { l = 1; base = 1024; }
  else if (bid < 1344) { l = 2; base = 1280; }
  else if (bid < 1360) { l = 3; base = 1344; }
  else                 { l = 4; base = 1360; }
  const int lg = D_LOG2G[l];
  const int g = 1 << lg, HW = 1 << (2 * lg);
  const int lognt = 2 * lg - 5;
  const int blk = bid - base;
  const int ct = blk >> lognt;
  const int tile = blk & ((1 << lognt) - 1);
  const int n0 = tile << 6;
  const int co0 = ct << 7;
  const int tid = threadIdx.x;
  const int wv = tid >> 6, lane = tid & 63;
  const u16* FtL = Ft + D_FTOFF[l];
  const u8* wpb = (const u8*)wp;
  const int b_img = n0 >> (2 * lg);            // tiles never cross images
  // B slot geometry: slot s0=tid covers pos nl0, quarter dq; s1=tid+128 -> nl1
  const int dq = tid & 3;
  const int nl0 = tid >> 2, nl1 = nl0 + 32;
  const int swz0 = (dq ^ ((nl0 >> 1) & 3)) << 3;
  const int swz1 = (dq ^ ((nl1 >> 1) & 3)) << 3;
  const int pg0 = (n0 + nl0) & (HW - 1);
  const int h0 = pg0 >> lg, w0 = pg0 & (g - 1);
  const int pg1 = (n0 + nl1) & (HW - 1);
  const int h1 = pg1 >> lg, w1 = pg1 & (g - 1);
  const u16* bimg = FtL + (size_t)b_img * (HW + 1) * 256;
  // fragment LDS byte offsets (K-step invariant)
  const int lm = lane & 15, lq = lane >> 4;
  int aoffs[4], boffs[4];
  #pragma unroll
  for (int mi = 0; mi < 4; ++mi) {
    int row = wv * 64 + mi * 16 + lm;
    aoffs[mi] = row * 64 + ((lq ^ ((row >> 1) & 3)) << 4);
  }
  #pragma unroll
  for (int ni = 0; ni < 4; ++ni) {
    int col = ni * 16 + lm;
    boffs[ni] = col * 64 + ((lq ^ ((col >> 1) & 3)) << 4);
  }
  f32x4 acc[4][4];
  #pragma unroll
  for (int mi = 0; mi < 4; ++mi)
    #pragma unroll
    for (int ni = 0; ni < 4; ++ni) acc[mi][ni] = (f32x4)0.f;

  for (int tap = 0; tap < 9; ++tap) {
    const int dh = tap / 3 - 1, dw = tap % 3 - 1;
    int sh0 = h0 + dh, sw0 = w0 + dw;
    int r0 = ((unsigned)sh0 < (unsigned)g && (unsigned)sw0 < (unsigned)g) ? (sh0 * g + sw0) : HW;
    int sh1 = h1 + dh, sw1 = w1 + dw;
    int r1 = ((unsigned)sh1 < (unsigned)g && (unsigned)sw1 < (unsigned)g) ? (sh1 * g + sw1) : HW;
    const u16* src0 = bimg + (size_t)r0 * 256 + swz0;
    const u16* src1 = bimg + (size_t)r1 * 256 + swz1;
    const u8* aS = wpb + (size_t)(tap * 8) * 16384 + co0 * 64;
    for (int cb8 = 0; cb8 < 8; ++cb8) {
      __syncthreads();
      glds16(src0 + cb8 * 32, Bsb + wv * 1024);
      glds16(src1 + cb8 * 32, Bsb + (2 + wv) * 1024);
      const u8* aK = aS + (size_t)cb8 * 16384;
      #pragma unroll
      for (int c = 0; c < 4; ++c) {
        int ch = c * 2 + wv;
        glds16(aK + ch * 1024 + lane * 16, Asb + ch * 1024);
      }
      __syncthreads();
      bf16x8 af[4], bfr[4];
      #pragma unroll
      for (int mi = 0; mi < 4; ++mi) af[mi] = *(const bf16x8*)(Asb + aoffs[mi]);
      #pragma unroll
      for (int ni = 0; ni < 4; ++ni) bfr[ni] = *(const bf16x8*)(Bsb + boffs[ni]);
      #pragma unroll
      for (int mi = 0; mi < 4; ++mi)
        #pragma unroll
        for (int ni = 0; ni < 4; ++ni)
          acc[mi][ni] = __builtin_amdgcn_mfma_f32_16x16x32_bf16(af[mi], bfr[ni], acc[mi][ni], 0, 0, 0);
    }
  }
  // epilogue: bias + relu + bf16 store to t[l][b][co][pos]
  u16* tL = t + D_TOFF[l] + (size_t)b_img * 256 * HW;
  #pragma unroll
  for (int mi = 0; mi < 4; ++mi) {
    #pragma unroll
    for (int r = 0; r < 4; ++r) {
      int co = co0 + wv * 64 + mi * 16 + lq * 4 + r;
      float bias = cb[co];
      u16* orow = tL + (size_t)co * HW;
      #pragma unroll
      for (int ni = 0; ni < 4; ++ni) {
        int pp = (n0 + ni * 16 + lm) & (HW - 1);
        float v = acc[mi][ni][r] + bias;
        orow[pp] = f2bf(fmaxf(v, 0.f));
      }
    }
  }
}

// ---------------- kernel: 1x1 heads (bf16 t input) -> preds[b][r][5] ---------------
__global__ __launch_bounds__(256) void head_kernel(
    const u16* __restrict__ t,
    const float* __restrict__ cls_w, const float* __restrict__ cls_b,
    const float* __restrict__ box_w, const float* __restrict__ box_b,
    float* __restrict__ out) {
  __shared__ float Ts[256][32];
  int bid = blockIdx.x;
  int l, base;
  if (bid < 1024)      { l = 0; base = 0; }
  else if (bid < 1280) { l = 1; base = 1024; }
  else if (bid < 1344) { l = 2; base = 1280; }
  else if (bid < 1360) { l = 3; base = 1344; }
  else                 { l = 4; base = 1360; }
  const int lg  = D_LOG2G[l];
  const int HW  = 1 << (2 * lg);
  const int lnb = 2 * lg - 5;
  int blk = bid - base;
  int b   = blk >> lnb;
  int p0  = (blk & ((1 << lnb) - 1)) << 5;
  const u16* tb = t + D_TOFF[l] + (size_t)b * 256 * HW;
  const int tid = threadIdx.x;
  #pragma unroll
  for (int i = 0; i < 32; ++i) {
    int idx = tid + (i << 8);
    int pp  = idx & 31;
    int ci  = idx >> 5;
    Ts[ci][pp] = bf2f(tb[(size_t)ci * HW + p0 + pp]);
  }
  __syncthreads();
  const int p   = tid & 31;
  const int grp = tid >> 5;
  const int pg  = p0 + p;
  const size_t aoff = (size_t)D_AOFF[l];
  for (int oc = grp; oc < 75; oc += 8) {
    const float* wr  = (oc < 15) ? (cls_w + oc * 256) : (box_w + (oc - 15) * 256);
    const float bias = (oc < 15) ? cls_b[oc] : box_b[oc - 15];
    const float4* wr4 = (const float4*)wr;
    float acc = 0.f;
    #pragma unroll 8
    for (int c4 = 0; c4 < 64; ++c4) {
      float4 wv = wr4[c4];
      int ci = c4 << 2;
      acc += wv.x * Ts[ci][p];
      acc += wv.y * Ts[ci + 1][p];
      acc += wv.z * Ts[ci + 2][p];
      acc += wv.w * Ts[ci + 3][p];
    }
    acc += bias;
    size_t r; int comp;
    if (oc < 15) { r = aoff + (size_t)oc * HW + pg; comp = 0; }
    else { int o2 = oc - 15; r = aoff + (size_t)(o2 >> 2) * HW + pg; comp = 1 + (o2 & 3); }
    out[((size_t)b * R_TOTAL + r) * 5 + comp] = acc;
  }
}

// ---------------- kernel: per-anchor labels + matched ------------------------------
__global__ __launch_bounds__(256) void label_kernel(const float* __restrict__ gt,
                                                    float* __restrict__ out) {
  #pragma clang fp contract(off)
  __shared__ float gx[32][4];
  const int b = blockIdx.y;
  const int tid = threadIdx.x;
  if (tid < 32) {
    const float* gp = gt + ((size_t)b * 32 + tid) * 4;
    float x = gp[0], y = gp[1], w = gp[2], h = gp[3];
    gx[tid][0] = x; gx[tid][1] = y; gx[tid][2] = x + w; gx[tid][3] = y + h;
  }
  __syncthreads();
  int r = blockIdx.x * 256 + tid;
  if (r >= R_TOTAL) return;
  float ax1, ay1, ax2, ay2;
  anchor_box(r, ax1, ay1, ax2, ay2);
  float best = -1e30f; int bi = 0;
  for (int n = 0; n < 32; ++n) {
    float v = iou_f(ax1, ay1, ax2, ay2, gx[n][0], gx[n][1], gx[n][2], gx[n][3]);
    if (v > best) { best = v; bi = n; }
  }
  float lab = (best < 0.3f) ? 0.f : ((best > 0.7f) ? 1.f : -1.f);
  out[LAB_OFF + (size_t)b * R_TOTAL + r] = lab;
  float4 m; m.x = gx[bi][0]; m.y = gx[bi][1]; m.z = gx[bi][2]; m.w = gx[bi][3];
  *(float4*)&out[MAT_OFF + ((size_t)b * R_TOTAL + r) * 4] = m;
}

// ---------------- kernel: per-gt best-anchor partial argmax ------------------------
__global__ __launch_bounds__(256) void argmax_part_kernel(const float* __restrict__ gt,
                                                          float2* __restrict__ part) {
  #pragma clang fp contract(off)
  const int bn = blockIdx.x >> 3, chunk = blockIdx.x & 7;
  const int b = bn >> 5, n = bn & 31;
  const float* gp = gt + ((size_t)b * 32 + n) * 4;
  const float bx1 = gp[0], by1 = gp[1];
  const float bx2 = bx1 + gp[2], by2 = by1 + gp[3];
  const int r0 = chunk * 40920;
  float best = -1e30f; int bi = 0;
  for (int r = r0 + threadIdx.x; r < r0 + 40920; r += 256) {
    float ax1, ay1, ax2, ay2;
    anchor_box(r, ax1, ay1, ax2, ay2);
    float v = iou_f(ax1, ay1, ax2, ay2, bx1, by1, bx2, by2);
    if (v > best) { best = v; bi = r; }
  }
  __shared__ float sv[256];
  __shared__ int   si[256];
  sv[threadIdx.x] = best; si[threadIdx.x] = bi;
  __syncthreads();
  for (int s = 128; s > 0; s >>= 1) {
    if ((int)threadIdx.x < s) {
      float v2 = sv[threadIdx.x + s]; int i2 = si[threadIdx.x + s];
      float v1 = sv[threadIdx.x];     int i1 = si[threadIdx.x];
      if (v2 > v1 || (v2 == v1 && i2 < i1)) { sv[threadIdx.x] = v2; si[threadIdx.x] = i2; }
    }
    __syncthreads();
  }
  if (threadIdx.x == 0) part[blockIdx.x] = make_float2(sv[0], __int_as_float(si[0]));
}

// ---------------- kernel: finalize forced-positive labels --------------------------
__global__ __launch_bounds__(64) void argmax_final_kernel(const float* __restrict__ gt,
                                                          const float2* __restrict__ part,
                                                          float* __restrict__ out) {
  #pragma clang fp contract(off)
  const int t = threadIdx.x;
  if (t >= 64) return;
  const int b = t >> 5;
  float best = -1e30f; int bi = 0;
  for (int c = 0; c < 8; ++c) {
    float2 pv = part[t * 8 + c];
    if (pv.x > best) { best = pv.x; bi = __float_as_int(pv.y); }
  }
  float ax1, ay1, ax2, ay2;
  anchor_box(bi, ax1, ay1, ax2, ay2);
  float score = -1e30f;
  for (int n2 = 0; n2 < 32; ++n2) {
    const float* gp = gt + ((size_t)b * 32 + n2) * 4;
    float v = iou_f(ax1, ay1, ax2, ay2, gp[0], gp[1], gp[0] + gp[2], gp[1] + gp[3]);
    score = fmaxf(score, v);
  }
  out[LAB_OFF + (size_t)b * R_TOTAL + bi] = (score < 0.3f) ? 0.f : 1.f;
}

// ---------------- launch -----------------------------------------------------------
extern "C" void kernel_launch(void* const* d_in, const int* in_sizes, int n_in,
                              void* d_out, int out_size, void* d_ws, size_t ws_size,
                              hipStream_t stream) {
  const float* f0     = (const float*)d_in[1];
  const float* f1     = (const float*)d_in[2];
  const float* f2     = (const float*)d_in[3];
  const float* f3     = (const float*)d_in[4];
  const float* f4     = (const float*)d_in[5];
  const float* gt     = (const float*)d_in[6];
  const float* conv_w = (const float*)d_in[7];
  const float* conv_b = (const float*)d_in[8];
  const float* cls_w  = (const float*)d_in[9];
  const float* cls_b  = (const float*)d_in[10];
  const float* box_w  = (const float*)d_in[11];
  const float* box_b  = (const float*)d_in[12];
  float* out = (float*)d_out;
  u8* wsb = (u8*)d_ws;

  u16* wp = (u16*)wsb;                         // 1,179,648 B  (72*256*32 bf16)
  u16* Ft = (u16*)(wsb + 1179648);             // 22,352,896 B (11,176,448 bf16)
  u16* tb = (u16*)(wsb + 23532544);            // 22,347,776 B (11,173,888 bf16)
  float2* part = (float2*)(wsb + 45880320);    // 4 KB

  pack_w_kernel<<<2304, 256, 0, stream>>>(conv_w, wp);
  feat_pack_kernel<<<692, 256, 0, stream>>>(f0, f1, f2, f3, f4, Ft);
  conv_mfma_kernel<<<1364, 128, 0, stream>>>(Ft, wp, conv_b, tb);
  head_kernel<<<1364, 256, 0, stream>>>(tb, cls_w, cls_b, box_w, box_b, out);
  label_kernel<<<dim3(1279, 2), 256, 0, stream>>>(gt, out);
  argmax_part_kernel<<<512, 256, 0, stream>>>(gt, part);
  argmax_final_kernel<<<1, 64, 0, stream>>>(gt, part, out);
}

// Round 3
// 270.423 us; speedup vs baseline: 3.8579x; 1.4065x over previous
//
#include <hip/hip_runtime.h>

typedef unsigned short u16;
typedef unsigned char  u8;
typedef unsigned int   u32;
typedef __bf16 bf16x8 __attribute__((ext_vector_type(8)));
typedef float  f32x4  __attribute__((ext_vector_type(4)));
typedef u16    u16x8  __attribute__((ext_vector_type(8)));
typedef u16    u16x4  __attribute__((ext_vector_type(4)));

// ---------------- constants ----------------
#define R_TOTAL 327360
#define LAB_OFF 3273600   // 2*R*5
#define MAT_OFF 3928320   // LAB_OFF + 2*R

static __device__ const int    D_LOG2G[5] = {7, 6, 5, 4, 3};
static __device__ const size_t D_FTOFF[5] = {0, 8389120, 10486784, 11011584, 11143168};
static __device__ const int    D_TPOFF[5] = {0, 32768, 40960, 43008, 43520}; // pos units (x256 ch)
static __device__ const int    D_AOFF[5]  = {0, 245760, 307200, 322560, 326400};

static __device__ const float D_WH[15][2] = {
  {22.627416997969522f, 45.254833995939045f}, {32.f, 32.f},   {45.254833995939045f, 22.627416997969522f},
  {45.254833995939045f, 90.50966799187809f},  {64.f, 64.f},   {90.50966799187809f, 45.254833995939045f},
  {90.50966799187809f, 181.01933598375618f},  {128.f, 128.f}, {181.01933598375618f, 90.50966799187809f},
  {181.01933598375618f, 362.03867196751236f}, {256.f, 256.f}, {362.03867196751236f, 181.01933598375618f},
  {362.03867196751236f, 724.0773439350247f},  {512.f, 512.f}, {724.0773439350247f, 362.03867196751236f},
};

__device__ __forceinline__ u16 f2bf(float x) {          // RNE f32->bf16
  u32 u = __float_as_uint(x);
  u32 r = u + 0x7FFFu + ((u >> 16) & 1u);
  return (u16)(r >> 16);
}
__device__ __forceinline__ float bf2f(u16 v) { return __uint_as_float(((u32)v) << 16); }

__device__ __forceinline__ void glds16(const void* g, void* l) {
  __builtin_amdgcn_global_load_lds(
      (const __attribute__((address_space(1))) u32*)g,
      (__attribute__((address_space(3))) u32*)l, 16, 0, 0);
}

// ---------------- anchor decode (contract OFF) ----------------
__device__ inline void anchor_box(int r, float& x1, float& y1, float& x2, float& y2) {
  #pragma clang fp contract(off)
  int off, lg;
  if (r < 245760)      { off = 0;      lg = 7; }
  else if (r < 307200) { off = 245760; lg = 6; }
  else if (r < 322560) { off = 307200; lg = 5; }
  else if (r < 326400) { off = 322560; lg = 4; }
  else                 { off = 326400; lg = 3; }
  int rem  = r - off;
  int a    = rem >> (2 * lg);
  int rem2 = rem & ((1 << (2 * lg)) - 1);
  int i = rem2 >> lg;
  int j = rem2 & ((1 << lg) - 1);
  float stride = (float)(512 >> lg);
  float cx = (float)i * stride;
  float cy = (float)j * stride;
  float hw = D_WH[a][0] * 0.5f;
  float hh = D_WH[a][1] * 0.5f;
  x1 = cx - hw; y1 = cy - hh; x2 = cx + hw; y2 = cy + hh;
}

__device__ inline float iou_f(float ax1, float ay1, float ax2, float ay2,
                              float bx1, float by1, float bx2, float by2) {
  #pragma clang fp contract(off)
  float ltx = fmaxf(ax1, bx1), lty = fmaxf(ay1, by1);
  float rbx = fminf(ax2, bx2), rby = fminf(ay2, by2);
  float iw = fmaxf(rbx - ltx, 0.f);
  float ih = fmaxf(rby - lty, 0.f);
  float inter = iw * ih;
  float aa = (ax2 - ax1) * (ay2 - ay1);
  float ab = (bx2 - bx1) * (by2 - by1);
  return inter / (aa + ab - inter);
}

// ---------------- kernel: pack conv_w -> bf16 [ks][co][32] with quarter swizzle ----
__global__ __launch_bounds__(256) void pack_w_kernel(const float* __restrict__ cw,
                                                     u16* __restrict__ wp) {
  int idx = blockIdx.x * 256 + threadIdx.x;   // < 589824
  int ks  = idx >> 13;
  int rem = idx & 8191;
  int co  = rem >> 5;
  int k   = rem & 31;
  int tap = ks >> 3;
  int cb  = ks & 7;
  float v = cw[co * 2304 + (cb * 32 + k) * 9 + tap];
  int qd = k >> 3, wi = k & 7;
  int dq = qd ^ ((co >> 1) & 3);
  wp[(size_t)ks * 8192 + co * 32 + dq * 8 + wi] = f2bf(v);
}

// ---------------- kernel: pack head weights -> Wb bf16 [80][256] + bias[80] --------
__global__ __launch_bounds__(256) void pack_head_w(
    const float* __restrict__ cls_w, const float* __restrict__ cls_b,
    const float* __restrict__ box_w, const float* __restrict__ box_b,
    u16* __restrict__ Wb, float* __restrict__ hbias) {
  int idx = blockIdx.x * 256 + threadIdx.x;   // < 20480
  int row = idx >> 8, k = idx & 255;
  float v = (row < 15) ? cls_w[row * 256 + k] : (row < 75) ? box_w[(row - 15) * 256 + k] : 0.f;
  Wb[row * 256 + k] = f2bf(v);
  if (idx < 80) hbias[idx] = (idx < 15) ? cls_b[idx] : (idx < 75) ? box_b[idx - 15] : 0.f;
}

// ---------------- kernel: features [b][ci][p] f32 -> [b][p][ci] bf16 (+zero row) ---
__global__ __launch_bounds__(256) void feat_pack_kernel(
    const float* __restrict__ f0, const float* __restrict__ f1,
    const float* __restrict__ f2, const float* __restrict__ f3,
    const float* __restrict__ f4, u16* __restrict__ Ft) {
  __shared__ float tile[64][65];
  int bid = blockIdx.x;
  int l, base, nb1;
  if (bid < 514)      { l = 0; base = 0;   nb1 = 257; }
  else if (bid < 644) { l = 1; base = 514; nb1 = 65; }
  else if (bid < 678) { l = 2; base = 644; nb1 = 17; }
  else if (bid < 688) { l = 3; base = 678; nb1 = 5; }
  else                { l = 4; base = 688; nb1 = 2; }
  const int lg = D_LOG2G[l];
  const int HW = 1 << (2 * lg);
  int blk = bid - base;
  int b   = blk / nb1;
  int p0  = (blk - b * nb1) * 64;
  u16* dst = Ft + D_FTOFF[l];
  const int tid = threadIdx.x;
  if (p0 >= HW) {      // zero halo row
    if (tid < 32) {
      u16x8 z = (u16x8)0;
      *(u16x8*)(dst + ((size_t)b * (HW + 1) + HW) * 256 + tid * 8) = z;
    }
    return;
  }
  const float* fsel = (l == 0) ? f0 : (l == 1) ? f1 : (l == 2) ? f2 : (l == 3) ? f3 : f4;
  const float* fb = fsel + (size_t)b * 256 * HW;
  for (int cg = 0; cg < 4; ++cg) {
    __syncthreads();
    #pragma unroll
    for (int i = 0; i < 16; ++i) {
      int idx = i * 256 + tid;
      int cl = idx >> 6, pp = idx & 63;
      tile[cl][pp] = fb[(size_t)(cg * 64 + cl) * HW + p0 + pp];
    }
    __syncthreads();
    #pragma unroll
    for (int i = 0; i < 2; ++i) {
      int slot = i * 256 + tid;
      int pos = slot >> 3, ch = slot & 7;
      u16x8 v;
      #pragma unroll
      for (int j = 0; j < 8; ++j) v[j] = f2bf(tile[ch * 8 + j][pos]);
      *(u16x8*)(dst + ((size_t)b * (HW + 1) + p0 + pos) * 256 + cg * 64 + ch * 8) = v;
    }
  }
}

// ---------------- kernel: 3x3 conv via bf16 MFMA, BM=128 co x BN=64 pos, BK=32 -----
// epilogue writes t POSITION-MAJOR: tP[l][b][p][co] bf16
__global__ __launch_bounds__(128) void conv_mfma_kernel(
    const u16* __restrict__ Ft, const u16* __restrict__ wp,
    const float* __restrict__ cb, u16* __restrict__ tP) {
  __shared__ __align__(16) u8 Asb[8192];
  __shared__ __align__(16) u8 Bsb[4096];
  const int bid = blockIdx.x;
  int l, base;
  if (bid < 1024)      { l = 0; base = 0; }
  else if (bid < 1280) { l = 1; base = 1024; }
  else if (bid < 1344) { l = 2; base = 1280; }
  else if (bid < 1360) { l = 3; base = 1344; }
  else                 { l = 4; base = 1360; }
  const int lg = D_LOG2G[l];
  const int g = 1 << lg, HW = 1 << (2 * lg);
  const int lognt = 2 * lg - 5;
  const int blk = bid - base;
  const int ct = blk >> lognt;
  const int tile = blk & ((1 << lognt) - 1);
  const int n0 = tile << 6;
  const int co0 = ct << 7;
  const int tid = threadIdx.x;
  const int wv = tid >> 6, lane = tid & 63;
  const u16* FtL = Ft + D_FTOFF[l];
  const u8* wpb = (const u8*)wp;
  const int b_img = n0 >> (2 * lg);            // tiles never cross images
  const int dq = tid & 3;
  const int nl0 = tid >> 2, nl1 = nl0 + 32;
  const int swz0 = (dq ^ ((nl0 >> 1) & 3)) << 3;
  const int swz1 = (dq ^ ((nl1 >> 1) & 3)) << 3;
  const int pg0 = (n0 + nl0) & (HW - 1);
  const int h0 = pg0 >> lg, w0 = pg0 & (g - 1);
  const int pg1 = (n0 + nl1) & (HW - 1);
  const int h1 = pg1 >> lg, w1 = pg1 & (g - 1);
  const u16* bimg = FtL + (size_t)b_img * (HW + 1) * 256;
  const int lm = lane & 15, lq = lane >> 4;
  int aoffs[4], boffs[4];
  #pragma unroll
  for (int mi = 0; mi < 4; ++mi) {
    int row = wv * 64 + mi * 16 + lm;
    aoffs[mi] = row * 64 + ((lq ^ ((row >> 1) & 3)) << 4);
  }
  #pragma unroll
  for (int ni = 0; ni < 4; ++ni) {
    int col = ni * 16 + lm;
    boffs[ni] = col * 64 + ((lq ^ ((col >> 1) & 3)) << 4);
  }
  f32x4 acc[4][4];
  #pragma unroll
  for (int mi = 0; mi < 4; ++mi)
    #pragma unroll
    for (int ni = 0; ni < 4; ++ni) acc[mi][ni] = (f32x4)0.f;

  for (int tap = 0; tap < 9; ++tap) {
    const int dh = tap / 3 - 1, dw = tap % 3 - 1;
    int sh0 = h0 + dh, sw0 = w0 + dw;
    int r0 = ((unsigned)sh0 < (unsigned)g && (unsigned)sw0 < (unsigned)g) ? (sh0 * g + sw0) : HW;
    int sh1 = h1 + dh, sw1 = w1 + dw;
    int r1 = ((unsigned)sh1 < (unsigned)g && (unsigned)sw1 < (unsigned)g) ? (sh1 * g + sw1) : HW;
    const u16* src0 = bimg + (size_t)r0 * 256 + swz0;
    const u16* src1 = bimg + (size_t)r1 * 256 + swz1;
    const u8* aS = wpb + (size_t)(tap * 8) * 16384 + co0 * 64;
    for (int cb8 = 0; cb8 < 8; ++cb8) {
      __syncthreads();
      glds16(src0 + cb8 * 32, Bsb + wv * 1024);
      glds16(src1 + cb8 * 32, Bsb + (2 + wv) * 1024);
      const u8* aK = aS + (size_t)cb8 * 16384;
      #pragma unroll
      for (int c = 0; c < 4; ++c) {
        int ch = c * 2 + wv;
        glds16(aK + ch * 1024 + lane * 16, Asb + ch * 1024);
      }
      __syncthreads();
      bf16x8 af[4], bfr[4];
      #pragma unroll
      for (int mi = 0; mi < 4; ++mi) af[mi] = *(const bf16x8*)(Asb + aoffs[mi]);
      #pragma unroll
      for (int ni = 0; ni < 4; ++ni) bfr[ni] = *(const bf16x8*)(Bsb + boffs[ni]);
      #pragma unroll
      for (int mi = 0; mi < 4; ++mi)
        #pragma unroll
        for (int ni = 0; ni < 4; ++ni)
          acc[mi][ni] = __builtin_amdgcn_mfma_f32_16x16x32_bf16(af[mi], bfr[ni], acc[mi][ni], 0, 0, 0);
    }
  }
  // epilogue: bias + relu + bf16 store, position-major [p][co]
  u16* tPL = tP + ((size_t)D_TPOFF[l] + (size_t)b_img * HW) * 256;
  #pragma unroll
  for (int mi = 0; mi < 4; ++mi) {
    const int cob = co0 + wv * 64 + mi * 16 + lq * 4;
    const float4 bs = *(const float4*)&cb[cob];
    #pragma unroll
    for (int ni = 0; ni < 4; ++ni) {
      int pp = (n0 + ni * 16 + lm) & (HW - 1);
      u16x4 v;
      v[0] = f2bf(fmaxf(acc[mi][ni][0] + bs.x, 0.f));
      v[1] = f2bf(fmaxf(acc[mi][ni][1] + bs.y, 0.f));
      v[2] = f2bf(fmaxf(acc[mi][ni][2] + bs.z, 0.f));
      v[3] = f2bf(fmaxf(acc[mi][ni][3] + bs.w, 0.f));
      *(u16x4*)&tPL[(size_t)pp * 256 + cob] = v;
    }
  }
}

// ---------------- kernel: 1x1 heads via MFMA  (BM=80, BN=64, K=256) ----------------
// B tile staged 64pos x 256ch with 3-bit slot XOR swizzle; W frags from global.
__global__ __launch_bounds__(128) void head_mfma_kernel(
    const u16* __restrict__ tP, const u16* __restrict__ Wb,
    const float* __restrict__ hbias, float* __restrict__ out) {
  __shared__ __align__(16) u8 Bsb[32768];
  const int bid = blockIdx.x;
  int l, base;
  if (bid < 512)      { l = 0; base = 0; }
  else if (bid < 640) { l = 1; base = 512; }
  else if (bid < 672) { l = 2; base = 640; }
  else if (bid < 680) { l = 3; base = 672; }
  else                { l = 4; base = 680; }
  const int lg = D_LOG2G[l];
  const int HW = 1 << (2 * lg);
  const int blk = bid - base;
  const int n0 = blk << 6;             // global pos (2 images flattened)
  const int tid = threadIdx.x;
  const int wv = tid >> 6, lane = tid & 63;
  const int lm = lane & 15, lq = lane >> 4;
  const u16* src = tP + ((size_t)D_TPOFF[l] + n0) * 256;
  // stage B: 64 pos x 512B rows; phys 16B-slot sp holds data slot sp^(pos&7)
  #pragma unroll
  for (int i = 0; i < 16; ++i) {
    int c = wv + i * 2;
    int slot = c * 64 + lane;
    int pos = slot >> 5, sp = slot & 31;
    glds16(src + (size_t)pos * 256 + ((sp ^ (pos & 7)) << 3), Bsb + c * 1024);
  }
  __syncthreads();
  f32x4 acc[5][2];
  #pragma unroll
  for (int mi = 0; mi < 5; ++mi) { acc[mi][0] = (f32x4)0.f; acc[mi][1] = (f32x4)0.f; }
  for (int kb = 0; kb < 8; ++kb) {
    bf16x8 af[5], bfr[2];
    #pragma unroll
    for (int mi = 0; mi < 5; ++mi)
      af[mi] = *(const bf16x8*)&Wb[(mi * 16 + lm) * 256 + kb * 32 + lq * 8];
    #pragma unroll
    for (int ni = 0; ni < 2; ++ni) {
      int p_ = wv * 32 + ni * 16 + lm;
      bfr[ni] = *(const bf16x8*)(Bsb + p_ * 512 + (((kb * 4 + lq) ^ (p_ & 7)) << 4));
    }
    #pragma unroll
    for (int mi = 0; mi < 5; ++mi)
      #pragma unroll
      for (int ni = 0; ni < 2; ++ni)
        acc[mi][ni] = __builtin_amdgcn_mfma_f32_16x16x32_bf16(af[mi], bfr[ni], acc[mi][ni], 0, 0, 0);
  }
  // epilogue: scatter to preds[b][r][5]
  const int b   = n0 >> (2 * lg);
  const int pgb = n0 & (HW - 1);
  const size_t obase = (size_t)b * R_TOTAL;
  const int aoff = D_AOFF[l];
  #pragma unroll
  for (int mi = 0; mi < 5; ++mi) {
    #pragma unroll
    for (int r = 0; r < 4; ++r) {
      int oc = mi * 16 + lq * 4 + r;
      if (oc < 75) {
        float bs = hbias[oc];
        size_t rr; int comp;
        if (oc < 15) { rr = (size_t)aoff + (size_t)oc * HW; comp = 0; }
        else { int o2 = oc - 15; rr = (size_t)aoff + (size_t)(o2 >> 2) * HW; comp = 1 + (o2 & 3); }
        #pragma unroll
        for (int ni = 0; ni < 2; ++ni) {
          int pg = pgb + wv * 32 + ni * 16 + lm;
          out[(obase + rr + pg) * 5 + comp] = acc[mi][ni][r] + bs;
        }
      }
    }
  }
}

// ---------------- kernel: per-anchor labels + matched ------------------------------
__global__ __launch_bounds__(256) void label_kernel(const float* __restrict__ gt,
                                                    float* __restrict__ out) {
  #pragma clang fp contract(off)
  __shared__ float gx[32][4];
  const int b = blockIdx.y;
  const int tid = threadIdx.x;
  if (tid < 32) {
    const float* gp = gt + ((size_t)b * 32 + tid) * 4;
    float x = gp[0], y = gp[1], w = gp[2], h = gp[3];
    gx[tid][0] = x; gx[tid][1] = y; gx[tid][2] = x + w; gx[tid][3] = y + h;
  }
  __syncthreads();
  int r = blockIdx.x * 256 + tid;
  if (r >= R_TOTAL) return;
  float ax1, ay1, ax2, ay2;
  anchor_box(r, ax1, ay1, ax2, ay2);
  float best = -1e30f; int bi = 0;
  for (int n = 0; n < 32; ++n) {
    float v = iou_f(ax1, ay1, ax2, ay2, gx[n][0], gx[n][1], gx[n][2], gx[n][3]);
    if (v > best) { best = v; bi = n; }
  }
  float lab = (best < 0.3f) ? 0.f : ((best > 0.7f) ? 1.f : -1.f);
  out[LAB_OFF + (size_t)b * R_TOTAL + r] = lab;
  float4 m; m.x = gx[bi][0]; m.y = gx[bi][1]; m.z = gx[bi][2]; m.w = gx[bi][3];
  *(float4*)&out[MAT_OFF + ((size_t)b * R_TOTAL + r) * 4] = m;
}

// ---------------- kernel: per-gt best-anchor partial argmax ------------------------
__global__ __launch_bounds__(256) void argmax_part_kernel(const float* __restrict__ gt,
                                                          float2* __restrict__ part) {
  #pragma clang fp contract(off)
  const int bn = blockIdx.x >> 3, chunk = blockIdx.x & 7;
  const int b = bn >> 5, n = bn & 31;
  const float* gp = gt + ((size_t)b * 32 + n) * 4;
  const float bx1 = gp[0], by1 = gp[1];
  const float bx2 = bx1 + gp[2], by2 = by1 + gp[3];
  const int r0 = chunk * 40920;
  float best = -1e30f; int bi = 0;
  for (int r = r0 + threadIdx.x; r < r0 + 40920; r += 256) {
    float ax1, ay1, ax2, ay2;
    anchor_box(r, ax1, ay1, ax2, ay2);
    float v = iou_f(ax1, ay1, ax2, ay2, bx1, by1, bx2, by2);
    if (v > best) { best = v; bi = r; }
  }
  __shared__ float sv[256];
  __shared__ int   si[256];
  sv[threadIdx.x] = best; si[threadIdx.x] = bi;
  __syncthreads();
  for (int s = 128; s > 0; s >>= 1) {
    if ((int)threadIdx.x < s) {
      float v2 = sv[threadIdx.x + s]; int i2 = si[threadIdx.x + s];
      float v1 = sv[threadIdx.x];     int i1 = si[threadIdx.x];
      if (v2 > v1 || (v2 == v1 && i2 < i1)) { sv[threadIdx.x] = v2; si[threadIdx.x] = i2; }
    }
    __syncthreads();
  }
  if (threadIdx.x == 0) part[blockIdx.x] = make_float2(sv[0], __int_as_float(si[0]));
}

// ---------------- kernel: finalize forced-positive labels --------------------------
__global__ __launch_bounds__(64) void argmax_final_kernel(const float* __restrict__ gt,
                                                          const float2* __restrict__ part,
                                                          float* __restrict__ out) {
  #pragma clang fp contract(off)
  const int t = threadIdx.x;
  if (t >= 64) return;
  const int b = t >> 5;
  float best = -1e30f; int bi = 0;
  for (int c = 0; c < 8; ++c) {
    float2 pv = part[t * 8 + c];
    if (pv.x > best) { best = pv.x; bi = __float_as_int(pv.y); }
  }
  float ax1, ay1, ax2, ay2;
  anchor_box(bi, ax1, ay1, ax2, ay2);
  float score = -1e30f;
  for (int n2 = 0; n2 < 32; ++n2) {
    const float* gp = gt + ((size_t)b * 32 + n2) * 4;
    float v = iou_f(ax1, ay1, ax2, ay2, gp[0], gp[1], gp[0] + gp[2], gp[1] + gp[3]);
    score = fmaxf(score, v);
  }
  out[LAB_OFF + (size_t)b * R_TOTAL + bi] = (score < 0.3f) ? 0.f : 1.f;
}

// ---------------- launch -----------------------------------------------------------
extern "C" void kernel_launch(void* const* d_in, const int* in_sizes, int n_in,
                              void* d_out, int out_size, void* d_ws, size_t ws_size,
                              hipStream_t stream) {
  const float* f0     = (const float*)d_in[1];
  const float* f1     = (const float*)d_in[2];
  const float* f2     = (const float*)d_in[3];
  const float* f3     = (const float*)d_in[4];
  const float* f4     = (const float*)d_in[5];
  const float* gt     = (const float*)d_in[6];
  const float* conv_w = (const float*)d_in[7];
  const float* conv_b = (const float*)d_in[8];
  const float* cls_w  = (const float*)d_in[9];
  const float* cls_b  = (const float*)d_in[10];
  const float* box_w  = (const float*)d_in[11];
  const float* box_b  = (const float*)d_in[12];
  float* out = (float*)d_out;
  u8* wsb = (u8*)d_ws;

  u16*   wp    = (u16*)wsb;                      // 1,179,648 B
  u16*   Ft    = (u16*)(wsb + 1179648);          // 22,352,896 B
  u16*   tP    = (u16*)(wsb + 23532544);         // 22,347,776 B
  u16*   Wb    = (u16*)(wsb + 45880320);         // 40,960 B
  float* hbias = (float*)(wsb + 45921280);       // 320 B
  float2* part = (float2*)(wsb + 45921600);      // 4,096 B

  pack_w_kernel<<<2304, 256, 0, stream>>>(conv_w, wp);
  pack_head_w<<<80, 256, 0, stream>>>(cls_w, cls_b, box_w, box_b, Wb, hbias);
  feat_pack_kernel<<<692, 256, 0, stream>>>(f0, f1, f2, f3, f4, Ft);
  conv_mfma_kernel<<<1364, 128, 0, stream>>>(Ft, wp, conv_b, tP);
  head_mfma_kernel<<<682, 128, 0, stream>>>(tP, Wb, hbias, out);
  label_kernel<<<dim3(1279, 2), 256, 0, stream>>>(gt, out);
  argmax_part_kernel<<<512, 256, 0, stream>>>(gt, part);
  argmax_final_kernel<<<1, 64, 0, stream>>>(gt, part, out);
}

// Round 4
// 231.616 us; speedup vs baseline: 4.5043x; 1.1675x over previous
//
#include <hip/hip_runtime.h>

typedef unsigned short u16;
typedef unsigned char  u8;
typedef unsigned int   u32;
typedef __bf16 bf16x8 __attribute__((ext_vector_type(8)));
typedef float  f32x4  __attribute__((ext_vector_type(4)));
typedef u16    u16x8  __attribute__((ext_vector_type(8)));
typedef u16    u16x4  __attribute__((ext_vector_type(4)));

// ---------------- constants ----------------
#define R_TOTAL 327360
#define LAB_OFF 3273600   // 2*R*5
#define MAT_OFF 3928320   // LAB_OFF + 2*R
#define NLBLK   1279      // label blocks per image (1279*256 >= R_TOTAL)

static __device__ const int    D_LOG2G[5] = {7, 6, 5, 4, 3};
static __device__ const size_t D_FTOFF[5] = {0, 8389120, 10486784, 11011584, 11143168};
static __device__ const int    D_TPOFF[5] = {0, 32768, 40960, 43008, 43520}; // pos units (x256 ch)
static __device__ const int    D_AOFF[5]  = {0, 245760, 307200, 322560, 326400};

static __device__ const float D_WH[15][2] = {
  {22.627416997969522f, 45.254833995939045f}, {32.f, 32.f},   {45.254833995939045f, 22.627416997969522f},
  {45.254833995939045f, 90.50966799187809f},  {64.f, 64.f},   {90.50966799187809f, 45.254833995939045f},
  {90.50966799187809f, 181.01933598375618f},  {128.f, 128.f}, {181.01933598375618f, 90.50966799187809f},
  {181.01933598375618f, 362.03867196751236f}, {256.f, 256.f}, {362.03867196751236f, 181.01933598375618f},
  {362.03867196751236f, 724.0773439350247f},  {512.f, 512.f}, {724.0773439350247f, 362.03867196751236f},
};

__device__ __forceinline__ u16 f2bf(float x) {          // RNE f32->bf16
  u32 u = __float_as_uint(x);
  u32 r = u + 0x7FFFu + ((u >> 16) & 1u);
  return (u16)(r >> 16);
}
__device__ __forceinline__ float bf2f(u16 v) { return __uint_as_float(((u32)v) << 16); }

__device__ __forceinline__ void glds16(const void* g, void* l) {
  __builtin_amdgcn_global_load_lds(
      (const __attribute__((address_space(1))) u32*)g,
      (__attribute__((address_space(3))) u32*)l, 16, 0, 0);
}

// ---------------- anchor decode (contract OFF) ----------------
__device__ inline void anchor_box(int r, float& x1, float& y1, float& x2, float& y2) {
  #pragma clang fp contract(off)
  int off, lg;
  if (r < 245760)      { off = 0;      lg = 7; }
  else if (r < 307200) { off = 245760; lg = 6; }
  else if (r < 322560) { off = 307200; lg = 5; }
  else if (r < 326400) { off = 322560; lg = 4; }
  else                 { off = 326400; lg = 3; }
  int rem  = r - off;
  int a    = rem >> (2 * lg);
  int rem2 = rem & ((1 << (2 * lg)) - 1);
  int i = rem2 >> lg;
  int j = rem2 & ((1 << lg) - 1);
  float stride = (float)(512 >> lg);
  float cx = (float)i * stride;
  float cy = (float)j * stride;
  float hw = D_WH[a][0] * 0.5f;
  float hh = D_WH[a][1] * 0.5f;
  x1 = cx - hw; y1 = cy - hh; x2 = cx + hw; y2 = cy + hh;
}

__device__ inline float iou_f(float ax1, float ay1, float ax2, float ay2,
                              float bx1, float by1, float bx2, float by2) {
  #pragma clang fp contract(off)
  float ltx = fmaxf(ax1, bx1), lty = fmaxf(ay1, by1);
  float rbx = fminf(ax2, bx2), rby = fminf(ay2, by2);
  float iw = fmaxf(rbx - ltx, 0.f);
  float ih = fmaxf(rby - lty, 0.f);
  float inter = iw * ih;
  float aa = (ax2 - ax1) * (ay2 - ay1);
  float ab = (bx2 - bx1) * (by2 - by1);
  return inter / (aa + ab - inter);
}

// ---------------- kernel: pack conv_w + head weights (fused) -----------------------
// blocks 0..2303: conv_w -> bf16 [ks][co][32] quarter-swizzled
// blocks 2304..2383: head weights -> Wb bf16 [80][256] + bias[80]
__global__ __launch_bounds__(256) void pack_all_kernel(
    const float* __restrict__ cw, u16* __restrict__ wp,
    const float* __restrict__ cls_w, const float* __restrict__ cls_b,
    const float* __restrict__ box_w, const float* __restrict__ box_b,
    u16* __restrict__ Wb, float* __restrict__ hbias) {
  if (blockIdx.x < 2304) {
    int idx = blockIdx.x * 256 + threadIdx.x;   // < 589824
    int ks  = idx >> 13;
    int rem = idx & 8191;
    int co  = rem >> 5;
    int k   = rem & 31;
    int tap = ks >> 3;
    int cb  = ks & 7;
    float v = cw[co * 2304 + (cb * 32 + k) * 9 + tap];
    int qd = k >> 3, wi = k & 7;
    int dq = qd ^ ((co >> 1) & 3);
    wp[(size_t)ks * 8192 + co * 32 + dq * 8 + wi] = f2bf(v);
  } else {
    int idx = (blockIdx.x - 2304) * 256 + threadIdx.x;   // < 20480
    int row = idx >> 8, k = idx & 255;
    float v = (row < 15) ? cls_w[row * 256 + k] : (row < 75) ? box_w[(row - 15) * 256 + k] : 0.f;
    Wb[row * 256 + k] = f2bf(v);
    if (idx < 80) hbias[idx] = (idx < 15) ? cls_b[idx] : (idx < 75) ? box_b[idx - 15] : 0.f;
  }
}

// ---------------- kernel: features [b][ci][p] f32 -> [b][p][ci] bf16 (+zero row) ---
__global__ __launch_bounds__(256) void feat_pack_kernel(
    const float* __restrict__ f0, const float* __restrict__ f1,
    const float* __restrict__ f2, const float* __restrict__ f3,
    const float* __restrict__ f4, u16* __restrict__ Ft) {
  __shared__ float tile[64][65];
  int bid = blockIdx.x;
  int l, base, nb1;
  if (bid < 514)      { l = 0; base = 0;   nb1 = 257; }
  else if (bid < 644) { l = 1; base = 514; nb1 = 65; }
  else if (bid < 678) { l = 2; base = 644; nb1 = 17; }
  else if (bid < 688) { l = 3; base = 678; nb1 = 5; }
  else                { l = 4; base = 688; nb1 = 2; }
  const int lg = D_LOG2G[l];
  const int HW = 1 << (2 * lg);
  int blk = bid - base;
  int b   = blk / nb1;
  int p0  = (blk - b * nb1) * 64;
  u16* dst = Ft + D_FTOFF[l];
  const int tid = threadIdx.x;
  if (p0 >= HW) {      // zero halo row
    if (tid < 32) {
      u16x8 z = (u16x8)0;
      *(u16x8*)(dst + ((size_t)b * (HW + 1) + HW) * 256 + tid * 8) = z;
    }
    return;
  }
  const float* fsel = (l == 0) ? f0 : (l == 1) ? f1 : (l == 2) ? f2 : (l == 3) ? f3 : f4;
  const float* fb = fsel + (size_t)b * 256 * HW;
  for (int cg = 0; cg < 4; ++cg) {
    __syncthreads();
    #pragma unroll
    for (int i = 0; i < 16; ++i) {
      int idx = i * 256 + tid;
      int cl = idx >> 6, pp = idx & 63;
      tile[cl][pp] = fb[(size_t)(cg * 64 + cl) * HW + p0 + pp];
    }
    __syncthreads();
    #pragma unroll
    for (int i = 0; i < 2; ++i) {
      int slot = i * 256 + tid;
      int pos = slot >> 3, ch = slot & 7;
      u16x8 v;
      #pragma unroll
      for (int j = 0; j < 8; ++j) v[j] = f2bf(tile[ch * 8 + j][pos]);
      *(u16x8*)(dst + ((size_t)b * (HW + 1) + p0 + pos) * 256 + cg * 64 + ch * 8) = v;
    }
  }
}

// ---------------- kernel: 3x3 conv via bf16 MFMA, 2-phase double-buffered ----------
// BM=128 co x BN=64 pos, BK=32; 72 K-steps; stage(s+1) issued before compute(s).
__global__ __launch_bounds__(128) void conv_mfma_kernel(
    const u16* __restrict__ Ft, const u16* __restrict__ wp,
    const float* __restrict__ cb, u16* __restrict__ tP) {
  __shared__ __align__(16) u8 Asb[16384];   // 2 x 8KB
  __shared__ __align__(16) u8 Bsb[8192];    // 2 x 4KB
  const int bid = blockIdx.x;
  int l, base;
  if (bid < 1024)      { l = 0; base = 0; }
  else if (bid < 1280) { l = 1; base = 1024; }
  else if (bid < 1344) { l = 2; base = 1280; }
  else if (bid < 1360) { l = 3; base = 1344; }
  else                 { l = 4; base = 1360; }
  const int lg = D_LOG2G[l];
  const int g = 1 << lg, HW = 1 << (2 * lg);
  const int lognt = 2 * lg - 5;
  const int blk = bid - base;
  const int ct = blk >> lognt;
  const int tile = blk & ((1 << lognt) - 1);
  const int n0 = tile << 6;
  const int co0 = ct << 7;
  const int tid = threadIdx.x;
  const int wv = tid >> 6, lane = tid & 63;
  const u16* FtL = Ft + D_FTOFF[l];
  const u8* wpb = (const u8*)wp;
  const int b_img = n0 >> (2 * lg);            // tiles never cross images
  const int dq = tid & 3;
  const int nl0 = tid >> 2, nl1 = nl0 + 32;
  const int swz0 = (dq ^ ((nl0 >> 1) & 3)) << 3;
  const int swz1 = (dq ^ ((nl1 >> 1) & 3)) << 3;
  const int pg0 = (n0 + nl0) & (HW - 1);
  const int h0 = pg0 >> lg, w0 = pg0 & (g - 1);
  const int pg1 = (n0 + nl1) & (HW - 1);
  const int h1 = pg1 >> lg, w1 = pg1 & (g - 1);
  const u16* bimg = FtL + (size_t)b_img * (HW + 1) * 256;
  const int lm = lane & 15, lq = lane >> 4;
  int aoffs[4], boffs[4];
  #pragma unroll
  for (int mi = 0; mi < 4; ++mi) {
    int row = wv * 64 + mi * 16 + lm;
    aoffs[mi] = row * 64 + ((lq ^ ((row >> 1) & 3)) << 4);
  }
  #pragma unroll
  for (int ni = 0; ni < 4; ++ni) {
    int col = ni * 16 + lm;
    boffs[ni] = col * 64 + ((lq ^ ((col >> 1) & 3)) << 4);
  }
  f32x4 acc[4][4];
  #pragma unroll
  for (int mi = 0; mi < 4; ++mi)
    #pragma unroll
    for (int ni = 0; ni < 4; ++ni) acc[mi][ni] = (f32x4)0.f;

  // source pointers for a given tap
  auto tap_src = [&](int tap, const u16*& s0, const u16*& s1) {
    const int dh = tap / 3 - 1, dw = tap % 3 - 1;
    int sh0 = h0 + dh, sw0 = w0 + dw;
    int r0 = ((unsigned)sh0 < (unsigned)g && (unsigned)sw0 < (unsigned)g) ? (sh0 * g + sw0) : HW;
    int sh1 = h1 + dh, sw1 = w1 + dw;
    int r1 = ((unsigned)sh1 < (unsigned)g && (unsigned)sw1 < (unsigned)g) ? (sh1 * g + sw1) : HW;
    s0 = bimg + (size_t)r0 * 256 + swz0;
    s1 = bimg + (size_t)r1 * 256 + swz1;
  };
  auto STAGE = [&](int p, int tap_, int cb8_, const u16* s0, const u16* s1) {
    glds16(s0 + cb8_ * 32, Bsb + p * 4096 + wv * 1024);
    glds16(s1 + cb8_ * 32, Bsb + p * 4096 + (2 + wv) * 1024);
    const u8* aK = wpb + (size_t)(tap_ * 8 + cb8_) * 16384 + co0 * 64;
    #pragma unroll
    for (int c = 0; c < 4; ++c) {
      int ch = c * 2 + wv;
      glds16(aK + ch * 1024 + lane * 16, Asb + p * 8192 + ch * 1024);
    }
  };

  const u16 *cs0, *cs1;
  tap_src(0, cs0, cs1);
  int p = 0;
  STAGE(0, 0, 0, cs0, cs1);
  __syncthreads();

  for (int tap = 0; tap < 9; ++tap) {
    const u16 *ns0 = cs0, *ns1 = cs1;
    if (tap < 8) tap_src(tap + 1, ns0, ns1);
    #pragma unroll
    for (int cb8 = 0; cb8 < 8; ++cb8) {
      if (!(tap == 8 && cb8 == 7)) {
        if (cb8 < 7) STAGE(p ^ 1, tap, cb8 + 1, cs0, cs1);
        else         STAGE(p ^ 1, tap + 1, 0, ns0, ns1);
      }
      bf16x8 af[4], bfr[4];
      #pragma unroll
      for (int mi = 0; mi < 4; ++mi) af[mi] = *(const bf16x8*)(Asb + p * 8192 + aoffs[mi]);
      #pragma unroll
      for (int ni = 0; ni < 4; ++ni) bfr[ni] = *(const bf16x8*)(Bsb + p * 4096 + boffs[ni]);
      #pragma unroll
      for (int mi = 0; mi < 4; ++mi)
        #pragma unroll
        for (int ni = 0; ni < 4; ++ni)
          acc[mi][ni] = __builtin_amdgcn_mfma_f32_16x16x32_bf16(af[mi], bfr[ni], acc[mi][ni], 0, 0, 0);
      __syncthreads();
      p ^= 1;
    }
    cs0 = ns0; cs1 = ns1;
  }
  // epilogue: bias + relu + bf16 store, position-major [p][co]
  u16* tPL = tP + ((size_t)D_TPOFF[l] + (size_t)b_img * HW) * 256;
  #pragma unroll
  for (int mi = 0; mi < 4; ++mi) {
    const int cob = co0 + wv * 64 + mi * 16 + lq * 4;
    const float4 bs = *(const float4*)&cb[cob];
    #pragma unroll
    for (int ni = 0; ni < 4; ++ni) {
      int pp = (n0 + ni * 16 + lm) & (HW - 1);
      u16x4 v;
      v[0] = f2bf(fmaxf(acc[mi][ni][0] + bs.x, 0.f));
      v[1] = f2bf(fmaxf(acc[mi][ni][1] + bs.y, 0.f));
      v[2] = f2bf(fmaxf(acc[mi][ni][2] + bs.z, 0.f));
      v[3] = f2bf(fmaxf(acc[mi][ni][3] + bs.w, 0.f));
      *(u16x4*)&tPL[(size_t)pp * 256 + cob] = v;
    }
  }
}

// ---------------- kernel: 1x1 heads via MFMA  (BM=80, BN=64, K=256) ----------------
__global__ __launch_bounds__(128) void head_mfma_kernel(
    const u16* __restrict__ tP, const u16* __restrict__ Wb,
    const float* __restrict__ hbias, float* __restrict__ out) {
  __shared__ __align__(16) u8 Bsb[32768];
  const int bid = blockIdx.x;
  int l, base;
  if (bid < 512)      { l = 0; base = 0; }
  else if (bid < 640) { l = 1; base = 512; }
  else if (bid < 672) { l = 2; base = 640; }
  else if (bid < 680) { l = 3; base = 672; }
  else                { l = 4; base = 680; }
  const int lg = D_LOG2G[l];
  const int HW = 1 << (2 * lg);
  const int blk = bid - base;
  const int n0 = blk << 6;             // global pos (2 images flattened)
  const int tid = threadIdx.x;
  const int wv = tid >> 6, lane = tid & 63;
  const int lm = lane & 15, lq = lane >> 4;
  const u16* src = tP + ((size_t)D_TPOFF[l] + n0) * 256;
  #pragma unroll
  for (int i = 0; i < 16; ++i) {
    int c = wv + i * 2;
    int slot = c * 64 + lane;
    int pos = slot >> 5, sp = slot & 31;
    glds16(src + (size_t)pos * 256 + ((sp ^ (pos & 7)) << 3), Bsb + c * 1024);
  }
  __syncthreads();
  f32x4 acc[5][2];
  #pragma unroll
  for (int mi = 0; mi < 5; ++mi) { acc[mi][0] = (f32x4)0.f; acc[mi][1] = (f32x4)0.f; }
  for (int kb = 0; kb < 8; ++kb) {
    bf16x8 af[5], bfr[2];
    #pragma unroll
    for (int mi = 0; mi < 5; ++mi)
      af[mi] = *(const bf16x8*)&Wb[(mi * 16 + lm) * 256 + kb * 32 + lq * 8];
    #pragma unroll
    for (int ni = 0; ni < 2; ++ni) {
      int p_ = wv * 32 + ni * 16 + lm;
      bfr[ni] = *(const bf16x8*)(Bsb + p_ * 512 + (((kb * 4 + lq) ^ (p_ & 7)) << 4));
    }
    #pragma unroll
    for (int mi = 0; mi < 5; ++mi)
      #pragma unroll
      for (int ni = 0; ni < 2; ++ni)
        acc[mi][ni] = __builtin_amdgcn_mfma_f32_16x16x32_bf16(af[mi], bfr[ni], acc[mi][ni], 0, 0, 0);
  }
  const int b   = n0 >> (2 * lg);
  const int pgb = n0 & (HW - 1);
  const size_t obase = (size_t)b * R_TOTAL;
  const int aoff = D_AOFF[l];
  #pragma unroll
  for (int mi = 0; mi < 5; ++mi) {
    #pragma unroll
    for (int r = 0; r < 4; ++r) {
      int oc = mi * 16 + lq * 4 + r;
      if (oc < 75) {
        float bs = hbias[oc];
        size_t rr; int comp;
        if (oc < 15) { rr = (size_t)aoff + (size_t)oc * HW; comp = 0; }
        else { int o2 = oc - 15; rr = (size_t)aoff + (size_t)(o2 >> 2) * HW; comp = 1 + (o2 & 3); }
        #pragma unroll
        for (int ni = 0; ni < 2; ++ni) {
          int pg = pgb + wv * 32 + ni * 16 + lm;
          out[(obase + rr + pg) * 5 + comp] = acc[mi][ni][r] + bs;
        }
      }
    }
  }
}

// ---------------- kernel: labels + matched + per-gt block partials (fused) ---------
__global__ __launch_bounds__(256) void label_fused_kernel(const float* __restrict__ gt,
                                                          float* __restrict__ out,
                                                          float2* __restrict__ partial) {
  #pragma clang fp contract(off)
  __shared__ float gx[32][4];
  __shared__ float sh[256][33];
  __shared__ float2 red[32][8];
  const int b = blockIdx.y;
  const int tid = threadIdx.x;
  if (tid < 32) {
    const float* gp = gt + ((size_t)b * 32 + tid) * 4;
    float x = gp[0], y = gp[1], w = gp[2], h = gp[3];
    gx[tid][0] = x; gx[tid][1] = y; gx[tid][2] = x + w; gx[tid][3] = y + h;
  }
  __syncthreads();
  const int r = blockIdx.x * 256 + tid;
  const bool valid = (r < R_TOTAL);
  const int rv = valid ? r : 0;
  float ax1, ay1, ax2, ay2;
  anchor_box(rv, ax1, ay1, ax2, ay2);
  float best = -1e30f; int bi = 0;
  for (int n = 0; n < 32; ++n) {
    float v = iou_f(ax1, ay1, ax2, ay2, gx[n][0], gx[n][1], gx[n][2], gx[n][3]);
    sh[tid][n] = valid ? v : -1e30f;
    if (v > best) { best = v; bi = n; }    // first-max (matches jnp.argmax)
  }
  if (valid) {
    float lab = (best < 0.3f) ? 0.f : ((best > 0.7f) ? 1.f : -1.f);
    out[LAB_OFF + (size_t)b * R_TOTAL + r] = lab;
    float4 m; m.x = gx[bi][0]; m.y = gx[bi][1]; m.z = gx[bi][2]; m.w = gx[bi][3];
    *(float4*)&out[MAT_OFF + ((size_t)b * R_TOTAL + r) * 4] = m;
  }
  __syncthreads();
  // phase 2: per-gt max over this block's 256 anchors
  const int n = tid & 31, gr = tid >> 5;
  float bv = -1e30f; int li = 0;
  #pragma unroll 4
  for (int a = 0; a < 32; ++a) {
    int la = gr * 32 + a;
    float v = sh[la][n];
    if (v > bv) { bv = v; li = la; }       // ascending scan keeps first-max
  }
  red[n][gr] = make_float2(bv, __int_as_float(li));
  __syncthreads();
  if (tid < 32) {
    float fv = -1e30f; int fi = 0;
    #pragma unroll
    for (int g2 = 0; g2 < 8; ++g2) {
      float2 pv = red[tid][g2];
      int ii = __float_as_int(pv.y);
      if (pv.x > fv) { fv = pv.x; fi = ii; }   // g2 ascending => idx ascending
    }
    partial[(size_t)(b * 32 + tid) * NLBLK + blockIdx.x] =
        make_float2(fv, __int_as_float(blockIdx.x * 256 + fi));
  }
}

// ---------------- kernel: finalize forced-positive labels --------------------------
__global__ __launch_bounds__(256) void argmax_final2_kernel(
    const float* __restrict__ gt, const float2* __restrict__ partial,
    float* __restrict__ out) {
  #pragma clang fp contract(off)
  __shared__ float sv[256];
  __shared__ int   si[256];
  const int b = blockIdx.x >> 5, n = blockIdx.x & 31;
  const float2* pp = partial + (size_t)(b * 32 + n) * NLBLK;
  const int tid = threadIdx.x;
  float bv = -1e30f; int bi = 0x7fffffff;
  for (int i = tid; i < NLBLK; i += 256) {
    float2 pv = pp[i]; int ii = __float_as_int(pv.y);
    if (pv.x > bv || (pv.x == bv && ii < bi)) { bv = pv.x; bi = ii; }
  }
  sv[tid] = bv; si[tid] = bi;
  __syncthreads();
  for (int s = 128; s > 0; s >>= 1) {
    if (tid < s) {
      float v2 = sv[tid + s]; int i2 = si[tid + s];
      if (v2 > sv[tid] || (v2 == sv[tid] && i2 < si[tid])) { sv[tid] = v2; si[tid] = i2; }
    }
    __syncthreads();
  }
  if (tid == 0) {
    int banch = si[0];
    float ax1, ay1, ax2, ay2;
    anchor_box(banch, ax1, ay1, ax2, ay2);
    float score = -1e30f;
    for (int n2 = 0; n2 < 32; ++n2) {
      const float* gp = gt + ((size_t)b * 32 + n2) * 4;
      float v = iou_f(ax1, ay1, ax2, ay2, gp[0], gp[1], gp[0] + gp[2], gp[1] + gp[3]);
      score = fmaxf(score, v);
    }
    out[LAB_OFF + (size_t)b * R_TOTAL + banch] = (score < 0.3f) ? 0.f : 1.f;
  }
}

// ---------------- launch -----------------------------------------------------------
extern "C" void kernel_launch(void* const* d_in, const int* in_sizes, int n_in,
                              void* d_out, int out_size, void* d_ws, size_t ws_size,
                              hipStream_t stream) {
  const float* f0     = (const float*)d_in[1];
  const float* f1     = (const float*)d_in[2];
  const float* f2     = (const float*)d_in[3];
  const float* f3     = (const float*)d_in[4];
  const float* f4     = (const float*)d_in[5];
  const float* gt     = (const float*)d_in[6];
  const float* conv_w = (const float*)d_in[7];
  const float* conv_b = (const float*)d_in[8];
  const float* cls_w  = (const float*)d_in[9];
  const float* cls_b  = (const float*)d_in[10];
  const float* box_w  = (const float*)d_in[11];
  const float* box_b  = (const float*)d_in[12];
  float* out = (float*)d_out;
  u8* wsb = (u8*)d_ws;

  u16*    wp      = (u16*)wsb;                      // 1,179,648 B
  u16*    Ft      = (u16*)(wsb + 1179648);          // 22,352,896 B
  u16*    tP      = (u16*)(wsb + 23532544);         // 22,347,776 B
  u16*    Wb      = (u16*)(wsb + 45880320);         // 40,960 B
  float*  hbias   = (float*)(wsb + 45921280);       // 320 B
  float2* partial = (float2*)(wsb + 45921600);      // 2*32*1279*8 = 654,848 B

  pack_all_kernel<<<2384, 256, 0, stream>>>(conv_w, wp, cls_w, cls_b, box_w, box_b, Wb, hbias);
  feat_pack_kernel<<<692, 256, 0, stream>>>(f0, f1, f2, f3, f4, Ft);
  conv_mfma_kernel<<<1364, 128, 0, stream>>>(Ft, wp, conv_b, tP);
  head_mfma_kernel<<<682, 128, 0, stream>>>(tP, Wb, hbias, out);
  label_fused_kernel<<<dim3(NLBLK, 2), 256, 0, stream>>>(gt, out, partial);
  argmax_final2_kernel<<<64, 256, 0, stream>>>(gt, partial, out);
}